// Round 6
// baseline (241.925 us; speedup 1.0000x reference)
//
#include <hip/hip_runtime.h>
#include <math.h>

// Problem constants (B=4, T=4096, D=2048, K=4)
#define D_DIM 2048
#define T_DIM 4096
#define NT    512              // threads: block spans full D, float4/thread
#define NW    8                // waves per block
#define CH    4                // rows per chunk
#define NCH   8                // chunks per strip
#define STRIP (CH * NCH)       // 32 rows per block
#define ROW_F D_DIM
#define AS1 __attribute__((address_space(1)))
#define AS3 __attribute__((address_space(3)))

typedef float vfloat4 __attribute__((ext_vector_type(4)));

__device__ __forceinline__ float silu(float v) {
    return v * __builtin_amdgcn_rcpf(1.f + __expf(-v));
}

__device__ __forceinline__ void nt_store4(float* p, float a, float b, float c, float d) {
    vfloat4 v = { a, b, c, d };
    __builtin_nontemporal_store(v, (vfloat4*)p);
}

// R6: persistent-strip double-buffered streaming (T3/T4 counted-vmcnt on a
// streaming op). R5 proved global_load_lds is the only staging mechanism the
// compiler can't defeat, but its one-shot blocks fully drain vmcnt at every
// __syncthreads. Here each block owns 32 rows (grid=512, exactly 2/CU),
// processed as 8 chunks of 4 rows:
//   prologue: DMA chunk0+chunk1, halo (3 rows) via register loads + LDS tree
//   steady:   compute(c) from buf[c&1] | DMA(c+2) into buf[c&1] after a
//             barrier | s_waitcnt vmcnt(8) (NEVER 0) | s_barrier
// -> >=64 KB perpetually in flight per CU, conv window in registers across
// chunks (halo read amp 1.75x -> 1.09x), all 8 waves active in the reduce
// (2 waves per row, half-row each, 2-entry LDS combine).
__global__ __launch_bounds__(NT, 4) void fused_kernel(
    const float* __restrict__ x,
    const float* __restrict__ g,
    const float* __restrict__ w,
    float* __restrict__ out)
{
    const int b    = blockIdx.y;
    const int t0   = blockIdx.x * STRIP;
    const int tid  = threadIdx.x;
    const int d0   = tid * 4;
    const int lane = tid & 63;
    const int wid  = tid >> 6;

    __shared__ __align__(16) float buf[2][CH * ROW_F];   // 64 KiB double buffer
    __shared__ __align__(16) float hpart[3][NW];
    __shared__ __align__(16) float part[CH][2];

    const float* xb = x   + (size_t)b * T_DIM * D_DIM;
    float*       ob = out + (size_t)b * T_DIM * D_DIM + d0;

    // ---- params ----
    const float4 gv = *(const float4*)(g + d0);
    float wgt[4][4];
#pragma unroll
    for (int j = 0; j < 4; ++j) {
        float4 wv = *(const float4*)(w + (size_t)(d0 + j) * 4);
        wgt[j][0] = wv.x; wgt[j][1] = wv.y; wgt[j][2] = wv.z; wgt[j][3] = wv.w;
    }

    // ---- halo rows t0-3..t0-1: register loads + classic 8-wave LDS tree ----
    float4 hv[3];
#pragma unroll
    for (int r = 0; r < 3; ++r) {
        const int t = t0 - 3 + r;   // block-uniform condition
        hv[r] = (t >= 0) ? *(const float4*)(xb + (size_t)t * D_DIM + d0)
                         : make_float4(0.f, 0.f, 0.f, 0.f);
    }
#pragma unroll
    for (int r = 0; r < 3; ++r) {
        float p = hv[r].x*hv[r].x + hv[r].y*hv[r].y + hv[r].z*hv[r].z + hv[r].w*hv[r].w;
#pragma unroll
        for (int off = 32; off > 0; off >>= 1) p += __shfl_down(p, off, 64);
        if (lane == 0) hpart[r][wid] = p;
    }
    __syncthreads();   // one-time full drain (prologue only)

    float win[3][4];
#pragma unroll
    for (int r = 0; r < 3; ++r) {
        const float* sp = hpart[r];
        const float s = sp[0]+sp[1]+sp[2]+sp[3]+sp[4]+sp[5]+sp[6]+sp[7];
        const float inv = rsqrtf(s * (1.0f / D_DIM) + 1e-5f);
        win[r][0] = hv[r].x * inv * gv.x;
        win[r][1] = hv[r].y * inv * gv.y;
        win[r][2] = hv[r].z * inv * gv.z;
        win[r][3] = hv[r].w * inv * gv.w;
    }

    // ---- prologue DMA: chunks 0 and 1 ----
#pragma unroll
    for (int cc = 0; cc < 2; ++cc) {
#pragma unroll
        for (int r = 0; r < CH; ++r) {
            const float* gsrc = xb + (size_t)(t0 + cc * CH + r) * D_DIM + d0;
            float* ldst = &buf[cc][r * ROW_F + d0];
            __builtin_amdgcn_global_load_lds((const AS1 void*)gsrc,
                                             (AS3 void*)ldst, 16, 0, 0);
        }
    }
    asm volatile("s_waitcnt vmcnt(4)" ::: "memory");   // chunk0 landed, chunk1 in flight
    __builtin_amdgcn_s_barrier();

    // ---- steady-state chunk loop ----
#pragma unroll
    for (int c = 0; c < NCH; ++c) {
        const float* bp = buf[c & 1];

        // half-row sumsq: wave (r = wid&3, h = wid>>2); all 8 waves active
        {
            const int r = wid & 3, h = wid >> 2;
            const float4* rp = (const float4*)(bp + r * ROW_F) + h * 256 + lane;
            float p = 0.f;
#pragma unroll
            for (int j = 0; j < 4; ++j) {
                float4 v = rp[j * 64];
                p = fmaf(v.x, v.x, p); p = fmaf(v.y, v.y, p);
                p = fmaf(v.z, v.z, p); p = fmaf(v.w, v.w, p);
            }
#pragma unroll
            for (int off = 32; off > 0; off >>= 1) p += __shfl_down(p, off, 64);
            if (lane == 0) part[r][h] = p;
        }
        asm volatile("s_waitcnt lgkmcnt(0)" ::: "memory");
        __builtin_amdgcn_s_barrier();

        // inv + normalize + conv + SiLU + store
        float inv[CH];
#pragma unroll
        for (int r = 0; r < CH; ++r)
            inv[r] = rsqrtf((part[r][0] + part[r][1]) * (1.0f / D_DIM) + 1e-5f);

        float n[CH][4];
#pragma unroll
        for (int r = 0; r < CH; ++r) {
            float4 v = *(const float4*)(bp + r * ROW_F + d0);   // conflict-free
            n[r][0] = v.x * inv[r] * gv.x;
            n[r][1] = v.y * inv[r] * gv.y;
            n[r][2] = v.z * inv[r] * gv.z;
            n[r][3] = v.w * inv[r] * gv.w;
        }
#pragma unroll
        for (int i = 0; i < CH; ++i) {
            float o[4];
#pragma unroll
            for (int j = 0; j < 4; ++j) {
                const float v = wgt[j][0] * win[0][j] + wgt[j][1] * win[1][j] +
                                wgt[j][2] * win[2][j] + wgt[j][3] * n[i][j];
                o[j] = silu(v);
            }
            nt_store4(ob + (size_t)(t0 + c * CH + i) * D_DIM, o[0], o[1], o[2], o[3]);
#pragma unroll
            for (int j = 0; j < 4; ++j) {
                win[0][j] = win[1][j]; win[1][j] = win[2][j]; win[2][j] = n[i][j];
            }
        }

        __builtin_amdgcn_sched_barrier(0);   // pin pipeline region ordering
        if (c <= NCH - 3) {
            __builtin_amdgcn_s_barrier();    // all waves done reading buf[c&1]
#pragma unroll
            for (int r = 0; r < CH; ++r) {   // DMA chunk c+2 into freed buffer
                const float* gsrc = xb + (size_t)(t0 + (c + 2) * CH + r) * D_DIM + d0;
                float* ldst = &buf[c & 1][r * ROW_F + d0];
                __builtin_amdgcn_global_load_lds((const AS1 void*)gsrc,
                                                 (AS3 void*)ldst, 16, 0, 0);
            }
            // outstanding: DMA(c+1)x4 | stores(c)x4 | DMA(c+2)x4 = 12 -> wait to 8
            // retires DMA(c+1) only; next chunk + stores stay in flight.
            asm volatile("s_waitcnt vmcnt(8)" ::: "memory");
            __builtin_amdgcn_s_barrier();
        } else if (c == NCH - 2) {
            // outstanding: DMA(7)x4 | stores(6)x4 = 8 -> wait to 4 retires DMA(7)
            asm volatile("s_waitcnt vmcnt(4)" ::: "memory");
            __builtin_amdgcn_s_barrier();
        }
    }
}

extern "C" void kernel_launch(void* const* d_in, const int* in_sizes, int n_in,
                              void* d_out, int out_size, void* d_ws, size_t ws_size,
                              hipStream_t stream) {
    const float* x = (const float*)d_in[0];
    const float* g = (const float*)d_in[1];   // norm_weight [D]
    const float* w = (const float*)d_in[2];   // conv_weight [D,1,K]
    float* out = (float*)d_out;

    const int total = in_sizes[0];            // B*T*D
    const int rows  = total / D_DIM;          // B*T
    const int B     = rows / T_DIM;

    dim3 grid(T_DIM / STRIP, B);              // 128 x 4 = 512 blocks = 2/CU
    fused_kernel<<<grid, NT, 0, stream>>>(x, g, w, out);
}